// Round 2
// baseline (567.834 us; speedup 1.0000x reference)
//
#include <hip/hip_runtime.h>
#include <hip/hip_bf16.h>

#define NB 4
#define LL 4096
#define SS 4096
#define CC 128

typedef unsigned short u16;
typedef __attribute__((ext_vector_type(8))) short  short8;
typedef __attribute__((ext_vector_type(4))) float  f32x4;
typedef __attribute__((ext_vector_type(4))) u16    u16x4;

// ---------- helpers ----------
__device__ __forceinline__ u16 f2bf(float f) {
  unsigned u = __float_as_uint(f);
  return (u16)((u + 0x7FFFu + ((u >> 16) & 1u)) >> 16);   // RNE, inputs are finite
}

__device__ __forceinline__ void gload_lds16(const void* g, void* l) {
  __builtin_amdgcn_global_load_lds(
      (const __attribute__((address_space(1))) unsigned*)g,
      (__attribute__((address_space(3))) unsigned*)l, 16, 0, 0);
}

// ---------- fp32 -> bf16 conversion of both feature tensors ----------
__global__ __launch_bounds__(256) void k_convert(const float* __restrict__ f0,
                                                 const float* __restrict__ f1,
                                                 u16* __restrict__ b0,
                                                 u16* __restrict__ b1) {
  const int i = blockIdx.x * 256 + threadIdx.x;
  const int n = NB * LL * CC / 4;
  if (i >= n) return;
  f32x4 x = ((const f32x4*)f0)[i];
  f32x4 y = ((const f32x4*)f1)[i];
  u16x4 a, c;
  a[0] = f2bf(x[0]); a[1] = f2bf(x[1]); a[2] = f2bf(x[2]); a[3] = f2bf(x[3]);
  c[0] = f2bf(y[0]); c[1] = f2bf(y[1]); c[2] = f2bf(y[2]); c[3] = f2bf(y[3]);
  ((u16x4*)b0)[i] = a;
  ((u16x4*)b1)[i] = c;
}

// ---------- bf16 MFMA GEMM: sim = f0 . f1^T / 128, fused exp-rowsum (v0 = 0) ----------
// 128x128 tile, K=128 fully staged in LDS (XOR-swizzled slots), 4 waves (2x2), each 64x64.
__global__ __launch_bounds__(256) void k_gemm(const u16* __restrict__ b0,
                                              const u16* __restrict__ b1,
                                              float* __restrict__ sim,
                                              float* __restrict__ rowacc) {
  __shared__ u16 lA[128 * 128];
  __shared__ u16 lB[128 * 128];
  const int bx = blockIdx.x, by = blockIdx.y, bz = blockIdx.z;
  const int tid = threadIdx.x;
  const int lane = tid & 63, wave = tid >> 6;

  const u16* gA = b0 + (size_t)bz * LL * CC + (size_t)by * 128 * CC;
  const u16* gB = b1 + (size_t)bz * SS * CC + (size_t)bx * 128 * CC;

  // stage both tiles: 2048 16B chunks each; LDS linear in chunk id, source pre-swizzled
#pragma unroll
  for (int i = 0; i < 8; ++i) {
    const int c = i * 256 + tid;          // chunk id
    const int row = c >> 4;               // tile row
    const int slot = c & 15;              // lds k-slot
    const int kchunk = slot ^ (row & 7);  // logical k-chunk stored at this slot
    const size_t soff = (size_t)row * CC + kchunk * 8;
    const int ldsoff = (i * 256 + wave * 64) * 16;  // wave-uniform byte base
    gload_lds16(gA + soff, (char*)lA + ldsoff);
    gload_lds16(gB + soff, (char*)lB + ldsoff);
  }
  __syncthreads();

  const int wr = wave >> 1, wc = wave & 1;
  f32x4 acc[4][4];
#pragma unroll
  for (int i = 0; i < 4; ++i)
#pragma unroll
    for (int j = 0; j < 4; ++j) acc[i][j] = (f32x4){0.f, 0.f, 0.f, 0.f};

#pragma unroll
  for (int ks = 0; ks < 4; ++ks) {
    short8 af[4], bfr[4];
#pragma unroll
    for (int mi = 0; mi < 4; ++mi) {
      const int row = wr * 64 + mi * 16 + (lane & 15);
      const int kc = ks * 4 + (lane >> 4);
      af[mi] = *(const short8*)&lA[row * 128 + (kc ^ (row & 7)) * 8];
    }
#pragma unroll
    for (int ni = 0; ni < 4; ++ni) {
      const int row = wc * 64 + ni * 16 + (lane & 15);
      const int kc = ks * 4 + (lane >> 4);
      bfr[ni] = *(const short8*)&lB[row * 128 + (kc ^ (row & 7)) * 8];
    }
#pragma unroll
    for (int mi = 0; mi < 4; ++mi)
#pragma unroll
      for (int ni = 0; ni < 4; ++ni)
        acc[mi][ni] = __builtin_amdgcn_mfma_f32_16x16x32_bf16(af[mi], bfr[ni], acc[mi][ni], 0, 0, 0);
  }

  // epilogue: scale, store, fused exp row-sums (v0 == 0)
  const float scale = 1.0f / 128.0f;
  const size_t obase = (size_t)bz * LL * SS;
#pragma unroll
  for (int mi = 0; mi < 4; ++mi) {
    float rs[4] = {0.f, 0.f, 0.f, 0.f};
    const int gr0 = by * 128 + wr * 64 + mi * 16 + (lane >> 4) * 4;
#pragma unroll
    for (int ni = 0; ni < 4; ++ni) {
      const int gc = bx * 128 + wc * 64 + ni * 16 + (lane & 15);
      f32x4 a = acc[mi][ni];
#pragma unroll
      for (int r = 0; r < 4; ++r) {
        const float val = a[r] * scale;
        sim[obase + (size_t)(gr0 + r) * SS + gc] = val;
        rs[r] += __expf(val);
      }
    }
#pragma unroll
    for (int m = 1; m < 16; m <<= 1)
#pragma unroll
      for (int r = 0; r < 4; ++r) rs[r] += __shfl_xor(rs[r], m, 64);
    if ((lane & 15) == 0) {
#pragma unroll
      for (int r = 0; r < 4; ++r)
        atomicAdd(&rowacc[bz * LL + gr0 + r], rs[r]);
    }
  }
}

// ---------- generic finalize:
//   outv[i]   = norm - log(acc[i] + exp(alpha + other[bin]))          (i < 4096)
//   outv[bin] = log(4096) + norm - (alpha + log(sum_i exp(other[i])))
// and, if ubin_next != null, pre-compute the NEXT u bin entry from the new outv:
//   ubin_next[b][bin] = log(4096) + norm - (alpha + log(sum_i exp(outv[i])))
__global__ void k_fin(const float* __restrict__ acc, const float* __restrict__ other,
                      float* __restrict__ outv, const float* __restrict__ alpha_p,
                      float* __restrict__ ubin_next) {
  const int b = blockIdx.x, t = threadIdx.x;
  const float alpha = *alpha_p;
  const float* ob = other + (size_t)b * 4097;
  const float* ab = acc + (size_t)b * 4096;
  float* vb = outv + (size_t)b * 4097;

  float s = 0.f;
  for (int i = t; i < 4097; i += 256) s += __expf(ob[i]);
  __shared__ float red[256];
  red[t] = s;
  __syncthreads();
  for (int o = 128; o > 0; o >>= 1) {
    if (t < o) red[t] += red[t + o];
    __syncthreads();
  }
  const float T = red[0];
  __syncthreads();

  const float norm = -logf(8192.0f);
  const float binterm = __expf(alpha + ob[4096]);
  float s2 = 0.f;
  for (int i = t; i < 4096; i += 256) {
    const float val = norm - __logf(ab[i] + binterm);
    vb[i] = val;
    s2 += __expf(val);
  }
  red[t] = s2;
  __syncthreads();
  for (int o = 128; o > 0; o >>= 1) {
    if (t < o) red[t] += red[t + o];
    __syncthreads();
  }
  if (t == 0) {
    const float vbin = logf(4096.0f) + norm - (alpha + __logf(T));
    vb[4096] = vbin;
    if (ubin_next != nullptr) {
      const float S = red[0] + __expf(vbin);
      ubin_next[(size_t)b * 4097 + 4096] = logf(4096.0f) + norm - (alpha + __logf(S));
    }
  }
}

// ---------- fused Sinkhorn pass: (optionally) u_k = rowLSE(v), then colacc += exp(sim+u_k) ----------
// 32 rows per block, 256 threads (4 waves x 8 rows in phase 1).
// NOTE: COMPUTE_U only writes the 4096 MAIN u entries; u[bin] was pre-written by
// the previous k_fin (ubin_next) from the same v this kernel reads.
template <bool COMPUTE_U>
__global__ __launch_bounds__(256) void k_rowcol(const float* __restrict__ sim,
                                                const float* __restrict__ v_g,
                                                float* __restrict__ u_g,
                                                float* __restrict__ colacc,
                                                const float* __restrict__ alpha_p) {
  __shared__ float v_lds[4096];
  __shared__ float u_lds[32];
  const int b = blockIdx.y, strip = blockIdx.x;
  const int t = threadIdx.x, lane = t & 63, wave = t >> 6;
  const float* simb = sim + (size_t)b * LL * SS + (size_t)strip * 32 * SS;
  const float* vb = v_g + (size_t)b * 4097;
  float* ub = u_g + (size_t)b * 4097;

  if (COMPUTE_U) {
    for (int i = t; i < 1024; i += 256) ((f32x4*)v_lds)[i] = ((const f32x4*)vb)[i];
    __syncthreads();
    const float alpha = *alpha_p;
    const float binterm = __expf(alpha + vb[4096]);
    const float norm = -logf(8192.0f);
    for (int rr = 0; rr < 8; ++rr) {
      const int rloc = wave * 8 + rr;
      const float* rowp = simb + (size_t)rloc * SS;
      float a = 0.f;
#pragma unroll
      for (int it = 0; it < 16; ++it) {
        f32x4 x = ((const f32x4*)rowp)[it * 64 + lane];
        f32x4 w = ((const f32x4*)v_lds)[it * 64 + lane];
        a += __expf(x[0] + w[0]) + __expf(x[1] + w[1]) + __expf(x[2] + w[2]) + __expf(x[3] + w[3]);
      }
#pragma unroll
      for (int m = 1; m < 64; m <<= 1) a += __shfl_xor(a, m, 64);
      if (lane == 0) {
        const float uval = norm - __logf(a + binterm);
        ub[strip * 32 + rloc] = uval;
        u_lds[rloc] = uval;
      }
    }
  } else {
    if (t < 32) u_lds[t] = ub[strip * 32 + t];
  }
  __syncthreads();

  float acc[16];
#pragma unroll
  for (int j = 0; j < 16; ++j) acc[j] = 0.f;
  for (int r = 0; r < 32; ++r) {
    const float uu = u_lds[r];
    const float* rowp = simb + (size_t)r * SS;
#pragma unroll
    for (int j = 0; j < 4; ++j) {
      f32x4 x = ((const f32x4*)rowp)[j * 256 + t];
      acc[j * 4 + 0] += __expf(x[0] + uu);
      acc[j * 4 + 1] += __expf(x[1] + uu);
      acc[j * 4 + 2] += __expf(x[2] + uu);
      acc[j * 4 + 3] += __expf(x[3] + uu);
    }
  }
  float* cb = colacc + (size_t)b * SS;
#pragma unroll
  for (int j = 0; j < 4; ++j) {
    const int c0 = j * 1024 + t * 4;
    atomicAdd(&cb[c0 + 0], acc[j * 4 + 0]);
    atomicAdd(&cb[c0 + 1], acc[j * 4 + 1]);
    atomicAdd(&cb[c0 + 2], acc[j * 4 + 2]);
    atomicAdd(&cb[c0 + 3], acc[j * 4 + 3]);
  }
}

// ---------- final: out = exp(sim + u[l] + v[s] - norm), in place ----------
__global__ __launch_bounds__(256) void k_final(float* __restrict__ sim,
                                               const float* __restrict__ u_g,
                                               const float* __restrict__ v_g) {
  __shared__ float v_lds[4096];
  const int b = blockIdx.y, t = threadIdx.x, lane = t & 63, wave = t >> 6;
  const float* vb = v_g + (size_t)b * 4097;
  const float* ub = u_g + (size_t)b * 4097;
  for (int i = t; i < 1024; i += 256) ((f32x4*)v_lds)[i] = ((const f32x4*)vb)[i];
  __syncthreads();
  const float norm = -logf(8192.0f);
  float* simb = sim + (size_t)b * LL * SS + (size_t)blockIdx.x * 16 * SS;
#pragma unroll
  for (int rr = 0; rr < 4; ++rr) {
    const int rloc = wave * 4 + rr;
    const float uval = ub[blockIdx.x * 16 + rloc] - norm;  // + (-norm) folded
    float* rowp = simb + (size_t)rloc * SS;
#pragma unroll
    for (int it = 0; it < 16; ++it) {
      f32x4 x = ((f32x4*)rowp)[it * 64 + lane];
      f32x4 w = ((const f32x4*)v_lds)[it * 64 + lane];
      f32x4 o;
      o[0] = __expf(x[0] + w[0] + uval);
      o[1] = __expf(x[1] + w[1] + uval);
      o[2] = __expf(x[2] + w[2] + uval);
      o[3] = __expf(x[3] + w[3] + uval);
      ((f32x4*)rowp)[it * 64 + lane] = o;
    }
  }
}

// ---------- launch ----------
extern "C" void kernel_launch(void* const* d_in, const int* in_sizes, int n_in,
                              void* d_out, int out_size, void* d_ws, size_t ws_size,
                              hipStream_t stream) {
  const float* f0 = (const float*)d_in[0];
  const float* f1 = (const float*)d_in[1];
  const float* alpha_p = (const float*)d_in[2];
  float* out = (float*)d_out;

  char* ws = (char*)d_ws;
  const size_t F1_OFF = (size_t)NB * LL * CC * 2;          // 4 MiB
  const size_t U_OFF = F1_OFF * 2;                         // 8 MiB
  const size_t V_OFF = U_OFF + (size_t)NB * 4097 * 4;
  const size_t RA_OFF = V_OFF + (size_t)NB * 4097 * 4;
  const size_t CA_OFF = RA_OFF + (size_t)NB * LL * 4;

  u16* b0 = (u16*)(ws);
  u16* b1 = (u16*)(ws + F1_OFF);
  float* u = (float*)(ws + U_OFF);
  float* v = (float*)(ws + V_OFF);
  float* rowacc = (float*)(ws + RA_OFF);
  float* colacc = (float*)(ws + CA_OFF);

  hipMemsetAsync(v, 0, (size_t)NB * 4097 * 4, stream);       // v0 = 0
  hipMemsetAsync(rowacc, 0, (size_t)NB * LL * 4, stream);

  k_convert<<<2048, 256, 0, stream>>>(f0, f1, b0, b1);

  dim3 gg(SS / 128, LL / 128, NB);
  k_gemm<<<gg, 256, 0, stream>>>(b0, b1, out, rowacc);

  // iteration 1: u1 from fused rowsums (v0=0), then col pass -> v1 (+ u_bin for iter 2)
  k_fin<<<NB, 256, 0, stream>>>(rowacc, v, u, alpha_p, nullptr);
  hipMemsetAsync(colacc, 0, (size_t)NB * SS * 4, stream);
  k_rowcol<false><<<dim3(LL / 32, NB), 256, 0, stream>>>(out, v, u, colacc, alpha_p);
  k_fin<<<NB, 256, 0, stream>>>(colacc, u, v, alpha_p, u);

  // iterations 2 and 3: fused row+col pass; each k_fin also refreshes the next u_bin
  for (int k = 0; k < 2; ++k) {
    hipMemsetAsync(colacc, 0, (size_t)NB * SS * 4, stream);
    k_rowcol<true><<<dim3(LL / 32, NB), 256, 0, stream>>>(out, v, u, colacc, alpha_p);
    k_fin<<<NB, 256, 0, stream>>>(colacc, u, v, alpha_p, u);
  }

  k_final<<<dim3(LL / 16, NB), 256, 0, stream>>>(out, u, v);
}

// Round 3
// 505.275 us; speedup vs baseline: 1.1238x; 1.1238x over previous
//
#include <hip/hip_runtime.h>
#include <hip/hip_bf16.h>
#include <hip/hip_fp16.h>

#define NB 4
#define LL 4096
#define SS 4096
#define CC 128

typedef unsigned short u16;
typedef _Float16 f16;
typedef __attribute__((ext_vector_type(8))) short  short8;
typedef __attribute__((ext_vector_type(8))) f16    f16x8;
typedef __attribute__((ext_vector_type(4))) float  f32x4;
typedef __attribute__((ext_vector_type(4))) u16    u16x4;

// ---------- helpers ----------
__device__ __forceinline__ u16 f2bf(float f) {
  unsigned u = __float_as_uint(f);
  return (u16)((u + 0x7FFFu + ((u >> 16) & 1u)) >> 16);   // RNE, inputs are finite
}

__device__ __forceinline__ void gload_lds16(const void* g, void* l) {
  __builtin_amdgcn_global_load_lds(
      (const __attribute__((address_space(1))) unsigned*)g,
      (__attribute__((address_space(3))) unsigned*)l, 16, 0, 0);
}

// ---------- fp32 -> bf16 conversion of both feature tensors ----------
__global__ __launch_bounds__(256) void k_convert(const float* __restrict__ f0,
                                                 const float* __restrict__ f1,
                                                 u16* __restrict__ b0,
                                                 u16* __restrict__ b1) {
  const int i = blockIdx.x * 256 + threadIdx.x;
  const int n = NB * LL * CC / 4;
  if (i >= n) return;
  f32x4 x = ((const f32x4*)f0)[i];
  f32x4 y = ((const f32x4*)f1)[i];
  u16x4 a, c;
  a[0] = f2bf(x[0]); a[1] = f2bf(x[1]); a[2] = f2bf(x[2]); a[3] = f2bf(x[3]);
  c[0] = f2bf(y[0]); c[1] = f2bf(y[1]); c[2] = f2bf(y[2]); c[3] = f2bf(y[3]);
  ((u16x4*)b0)[i] = a;
  ((u16x4*)b1)[i] = c;
}

// ---------- init ev0 = exp(v0) = 1 ----------
__global__ void k_init(float* __restrict__ ev) {
  const int i = blockIdx.x * 256 + threadIdx.x;
  if (i < NB * 4097) ev[i] = 1.0f;
}

// ---------- bf16 MFMA GEMM: E = exp(f0 . f1^T / 128) in fp16, fused rowsum (ev0 = 1) ----------
__global__ __launch_bounds__(256) void k_gemm(const u16* __restrict__ b0,
                                              const u16* __restrict__ b1,
                                              f16* __restrict__ E,
                                              float* __restrict__ rowacc) {
  __shared__ u16 lA[128 * 128];
  __shared__ u16 lB[128 * 128];
  const int bx = blockIdx.x, by = blockIdx.y, bz = blockIdx.z;
  const int tid = threadIdx.x;
  const int lane = tid & 63, wave = tid >> 6;

  const u16* gA = b0 + (size_t)bz * LL * CC + (size_t)by * 128 * CC;
  const u16* gB = b1 + (size_t)bz * SS * CC + (size_t)bx * 128 * CC;

#pragma unroll
  for (int i = 0; i < 8; ++i) {
    const int c = i * 256 + tid;
    const int row = c >> 4;
    const int slot = c & 15;
    const int kchunk = slot ^ (row & 7);
    const size_t soff = (size_t)row * CC + kchunk * 8;
    const int ldsoff = (i * 256 + wave * 64) * 16;
    gload_lds16(gA + soff, (char*)lA + ldsoff);
    gload_lds16(gB + soff, (char*)lB + ldsoff);
  }
  __syncthreads();

  const int wr = wave >> 1, wc = wave & 1;
  f32x4 acc[4][4];
#pragma unroll
  for (int i = 0; i < 4; ++i)
#pragma unroll
    for (int j = 0; j < 4; ++j) acc[i][j] = (f32x4){0.f, 0.f, 0.f, 0.f};

#pragma unroll
  for (int ks = 0; ks < 4; ++ks) {
    short8 af[4], bfr[4];
#pragma unroll
    for (int mi = 0; mi < 4; ++mi) {
      const int row = wr * 64 + mi * 16 + (lane & 15);
      const int kc = ks * 4 + (lane >> 4);
      af[mi] = *(const short8*)&lA[row * 128 + (kc ^ (row & 7)) * 8];
    }
#pragma unroll
    for (int ni = 0; ni < 4; ++ni) {
      const int row = wc * 64 + ni * 16 + (lane & 15);
      const int kc = ks * 4 + (lane >> 4);
      bfr[ni] = *(const short8*)&lB[row * 128 + (kc ^ (row & 7)) * 8];
    }
#pragma unroll
    for (int mi = 0; mi < 4; ++mi)
#pragma unroll
      for (int ni = 0; ni < 4; ++ni)
        acc[mi][ni] = __builtin_amdgcn_mfma_f32_16x16x32_bf16(af[mi], bfr[ni], acc[mi][ni], 0, 0, 0);
  }

  // epilogue: E = (f16)exp(sim); rowsum += (f32)E   (ev0 == 1)
  const float scale = 1.0f / 128.0f;
  const size_t obase = (size_t)bz * LL * SS;
#pragma unroll
  for (int mi = 0; mi < 4; ++mi) {
    float rs[4] = {0.f, 0.f, 0.f, 0.f};
    const int gr0 = by * 128 + wr * 64 + mi * 16 + (lane >> 4) * 4;
#pragma unroll
    for (int ni = 0; ni < 4; ++ni) {
      const int gc = bx * 128 + wc * 64 + ni * 16 + (lane & 15);
      f32x4 a = acc[mi][ni];
#pragma unroll
      for (int r = 0; r < 4; ++r) {
        const f16 eh = (f16)__expf(a[r] * scale);
        E[obase + (size_t)(gr0 + r) * SS + gc] = eh;
        rs[r] += (float)eh;
      }
    }
#pragma unroll
    for (int m = 1; m < 16; m <<= 1)
#pragma unroll
      for (int r = 0; r < 4; ++r) rs[r] += __shfl_xor(rs[r], m, 64);
    if ((lane & 15) == 0) {
#pragma unroll
      for (int r = 0; r < 4; ++r)
        atomicAdd(&rowacc[bz * LL + gr0 + r], rs[r]);
    }
  }
}

// ---------- finalize (exp domain):
//   oute[i]   = (1/8192) / (acc[i] + e^a * other[bin])     (i<4096), then acc[i]=0
//   oute[bin] = 0.5 * e^-a / (sum_{i<=4096} other[i])
//   eubin_next[bin] = 0.5 * e^-a / (sum_{i<=4096} oute[i])
__global__ void k_fin(float* __restrict__ acc, const float* __restrict__ other,
                      float* __restrict__ oute, const float* __restrict__ alpha_p,
                      float* __restrict__ eubin_next) {
  const int b = blockIdx.x, t = threadIdx.x;
  const float alpha = *alpha_p;
  const float* ob = other + (size_t)b * 4097;
  float* ab = acc + (size_t)b * 4096;
  float* vb = oute + (size_t)b * 4097;
  const float enorm = 1.0f / 8192.0f;

  float s = 0.f;
  for (int i = t; i < 4097; i += 256) s += ob[i];
  __shared__ float red[256];
  red[t] = s;
  __syncthreads();
  for (int o = 128; o > 0; o >>= 1) {
    if (t < o) red[t] += red[t + o];
    __syncthreads();
  }
  const float T = red[0];
  __syncthreads();

  const float bt = __expf(alpha) * ob[4096];
  float s2 = 0.f;
  for (int i = t; i < 4096; i += 256) {
    const float val = enorm / (ab[i] + bt);
    vb[i] = val;
    ab[i] = 0.f;             // leave acc zeroed for the next accumulation pass
    s2 += val;
  }
  red[t] = s2;
  __syncthreads();
  for (int o = 128; o > 0; o >>= 1) {
    if (t < o) red[t] += red[t + o];
    __syncthreads();
  }
  if (t == 0) {
    const float ebin = 0.5f * __expf(-alpha) / T;
    vb[4096] = ebin;
    if (eubin_next != nullptr)
      eubin_next[(size_t)b * 4097 + 4096] = 0.5f * __expf(-alpha) / (red[0] + ebin);
  }
}

// ---------- fused Sinkhorn pass (exp domain, fp16 E):
// phase1 (optional): eu[l] = (1/8192) / (E·ev + e^a*ev[bin]);  phase2: colacc += eu[l]*E
template <bool COMPUTE_U>
__global__ __launch_bounds__(256) void k_rowcol(const f16* __restrict__ E,
                                                const float* __restrict__ ev_g,
                                                float* __restrict__ eu_g,
                                                float* __restrict__ colacc,
                                                const float* __restrict__ alpha_p) {
  __shared__ float ev_lds[4096];
  __shared__ float eu_lds[32];
  const int b = blockIdx.y, strip = blockIdx.x;
  const int t = threadIdx.x, lane = t & 63, wave = t >> 6;
  const f16* Eb = E + (size_t)b * LL * SS + (size_t)strip * 32 * SS;
  const float* evb = ev_g + (size_t)b * 4097;
  float* ub = eu_g + (size_t)b * 4097;
  const float enorm = 1.0f / 8192.0f;

  if (COMPUTE_U) {
    for (int i = t; i < 1024; i += 256) ((f32x4*)ev_lds)[i] = ((const f32x4*)evb)[i];
    __syncthreads();
    const float bt = __expf(*alpha_p) * evb[4096];
    for (int rr = 0; rr < 8; ++rr) {
      const int rloc = wave * 8 + rr;
      const f16x8* rowp = (const f16x8*)(Eb + (size_t)rloc * SS);
      float a = 0.f;
#pragma unroll
      for (int it = 0; it < 8; ++it) {
        const f16x8 h = rowp[it * 64 + lane];
        const int base = (it * 64 + lane) * 8;
#pragma unroll
        for (int e = 0; e < 8; ++e) a += (float)h[e] * ev_lds[base + e];
      }
#pragma unroll
      for (int m = 1; m < 64; m <<= 1) a += __shfl_xor(a, m, 64);
      if (lane == 0) {
        const float eu = enorm / (a + bt);
        ub[strip * 32 + rloc] = eu;
        eu_lds[rloc] = eu;
      }
    }
  } else {
    if (t < 32) eu_lds[t] = ub[strip * 32 + t];
  }
  __syncthreads();

  float acc[16];
#pragma unroll
  for (int j = 0; j < 16; ++j) acc[j] = 0.f;
  for (int r = 0; r < 32; ++r) {
    const float a = eu_lds[r];
    const f16x8* rowp = (const f16x8*)(Eb + (size_t)r * SS);
#pragma unroll
    for (int j = 0; j < 2; ++j) {
      const f16x8 h = rowp[j * 256 + t];
#pragma unroll
      for (int e = 0; e < 8; ++e) acc[j * 8 + e] += a * (float)h[e];
    }
  }
  float* cb = colacc + (size_t)b * SS;
#pragma unroll
  for (int j = 0; j < 2; ++j) {
    const int c0 = (j * 256 + t) * 8;
#pragma unroll
    for (int e = 0; e < 8; ++e) atomicAdd(&cb[c0 + e], acc[j * 8 + e]);
  }
}

// ---------- final: out = E * eu[l] * ev[s] * 8192 ----------
__global__ __launch_bounds__(256) void k_final(const f16* __restrict__ E,
                                               float* __restrict__ out,
                                               const float* __restrict__ eu_g,
                                               const float* __restrict__ ev_g) {
  __shared__ float ev_lds[4096];
  const int b = blockIdx.y, t = threadIdx.x, lane = t & 63, wave = t >> 6;
  const float* evb = ev_g + (size_t)b * 4097;
  const float* ub = eu_g + (size_t)b * 4097;
  for (int i = t; i < 1024; i += 256) ((f32x4*)ev_lds)[i] = ((const f32x4*)evb)[i];
  __syncthreads();
  const size_t rbase = (size_t)b * LL * SS + (size_t)blockIdx.x * 16 * SS;
#pragma unroll
  for (int rr = 0; rr < 4; ++rr) {
    const int rloc = wave * 4 + rr;
    const float a = ub[blockIdx.x * 16 + rloc] * 8192.0f;
    const f16x8* rowp = (const f16x8*)(E + rbase + (size_t)rloc * SS);
    f32x4* orow = (f32x4*)(out + rbase + (size_t)rloc * SS);
#pragma unroll
    for (int it = 0; it < 8; ++it) {
      const f16x8 h = rowp[it * 64 + lane];
      const int base = (it * 64 + lane) * 8;
      f32x4 o0, o1;
#pragma unroll
      for (int e = 0; e < 4; ++e) o0[e] = (float)h[e] * a * ev_lds[base + e];
#pragma unroll
      for (int e = 0; e < 4; ++e) o1[e] = (float)h[4 + e] * a * ev_lds[base + 4 + e];
      orow[2 * (it * 64 + lane)] = o0;
      orow[2 * (it * 64 + lane) + 1] = o1;
    }
  }
}

// ---------- launch ----------
extern "C" void kernel_launch(void* const* d_in, const int* in_sizes, int n_in,
                              void* d_out, int out_size, void* d_ws, size_t ws_size,
                              hipStream_t stream) {
  const float* f0 = (const float*)d_in[0];
  const float* f1 = (const float*)d_in[1];
  const float* alpha_p = (const float*)d_in[2];
  float* out = (float*)d_out;

  char* ws = (char*)d_ws;
  const size_t E_SZ = (size_t)NB * LL * SS * 2;             // 128 MiB
  const size_t B0_OFF = E_SZ;
  const size_t B1_OFF = B0_OFF + (size_t)NB * LL * CC * 2;  // +4 MiB
  const size_t U_OFF = B1_OFF + (size_t)NB * SS * CC * 2;   // +4 MiB
  const size_t V_OFF = U_OFF + (size_t)NB * 4097 * 4;
  const size_t RA_OFF = (V_OFF + (size_t)NB * 4097 * 4 + 255) & ~(size_t)255;
  const size_t CA_OFF = RA_OFF + (size_t)NB * LL * 4;       // contiguous with RA

  f16* E = (f16*)ws;
  u16* b0 = (u16*)(ws + B0_OFF);
  u16* b1 = (u16*)(ws + B1_OFF);
  float* eu = (float*)(ws + U_OFF);
  float* ev = (float*)(ws + V_OFF);
  float* rowacc = (float*)(ws + RA_OFF);
  float* colacc = (float*)(ws + CA_OFF);

  // zero rowacc + colacc in one shot (contiguous)
  hipMemsetAsync(rowacc, 0, (size_t)NB * (LL + SS) * 4, stream);
  k_init<<<(NB * 4097 + 255) / 256, 256, 0, stream>>>(ev);   // ev0 = exp(0) = 1
  k_convert<<<2048, 256, 0, stream>>>(f0, f1, b0, b1);

  dim3 gg(SS / 128, LL / 128, NB);
  k_gemm<<<gg, 256, 0, stream>>>(b0, b1, E, rowacc);

  // iter 1: eu1 from fused rowsums (ev0=1); col pass -> ev1 (+ eu2 bin pre-write)
  k_fin<<<NB, 256, 0, stream>>>(rowacc, ev, eu, alpha_p, nullptr);
  k_rowcol<false><<<dim3(LL / 32, NB), 256, 0, stream>>>(E, ev, eu, colacc, alpha_p);
  k_fin<<<NB, 256, 0, stream>>>(colacc, eu, ev, alpha_p, eu);

  // iters 2,3: fused row+col pass; k_fin re-zeroes colacc and refreshes next eu_bin
  for (int k = 0; k < 2; ++k) {
    k_rowcol<true><<<dim3(LL / 32, NB), 256, 0, stream>>>(E, ev, eu, colacc, alpha_p);
    k_fin<<<NB, 256, 0, stream>>>(colacc, eu, ev, alpha_p, eu);
  }

  k_final<<<dim3(LL / 16, NB), 256, 0, stream>>>(E, out, eu, ev);
}

// Round 4
// 465.053 us; speedup vs baseline: 1.2210x; 1.0865x over previous
//
#include <hip/hip_runtime.h>
#include <hip/hip_bf16.h>
#include <hip/hip_fp16.h>

#define NB 4
#define LL 4096
#define SS 4096
#define CC 128

typedef unsigned short u16;
typedef _Float16 f16;
typedef __attribute__((ext_vector_type(8))) short  short8;
typedef __attribute__((ext_vector_type(8))) f16    f16x8;
typedef __attribute__((ext_vector_type(4))) float  f32x4;
typedef __attribute__((ext_vector_type(4))) u16    u16x4;

// ---------- helpers ----------
__device__ __forceinline__ u16 f2bf(float f) {
  unsigned u = __float_as_uint(f);
  return (u16)((u + 0x7FFFu + ((u >> 16) & 1u)) >> 16);   // RNE, inputs finite
}

__device__ __forceinline__ void gload_lds16(const void* g, void* l) {
  __builtin_amdgcn_global_load_lds(
      (const __attribute__((address_space(1))) unsigned*)g,
      (__attribute__((address_space(3))) unsigned*)l, 16, 0, 0);
}

template <int NW>
__device__ __forceinline__ float block_sum(float v, float* red, int t) {
#pragma unroll
  for (int m = 1; m < 64; m <<= 1) v += __shfl_xor(v, m, 64);
  if ((t & 63) == 0) red[t >> 6] = v;
  __syncthreads();
  float s = 0.f;
#pragma unroll
  for (int w = 0; w < NW; ++w) s += red[w];
  __syncthreads();
  return s;
}

// ---------- fp32 -> bf16 conversion ----------
__global__ __launch_bounds__(256) void k_convert(const float* __restrict__ f0,
                                                 const float* __restrict__ f1,
                                                 u16* __restrict__ b0,
                                                 u16* __restrict__ b1) {
  const int i = blockIdx.x * 256 + threadIdx.x;
  const int n = NB * LL * CC / 4;
  if (i >= n) return;
  f32x4 x = ((const f32x4*)f0)[i];
  f32x4 y = ((const f32x4*)f1)[i];
  u16x4 a, c;
  a[0] = f2bf(x[0]); a[1] = f2bf(x[1]); a[2] = f2bf(x[2]); a[3] = f2bf(x[3]);
  c[0] = f2bf(y[0]); c[1] = f2bf(y[1]); c[2] = f2bf(y[2]); c[3] = f2bf(y[3]);
  ((u16x4*)b0)[i] = a;
  ((u16x4*)b1)[i] = c;
}

// ---------- bf16 MFMA GEMM: E = exp(f0.f1^T/128) f16, fused rowsum, LDS-restaged stores ----------
__global__ __launch_bounds__(256) void k_gemm(const u16* __restrict__ b0,
                                              const u16* __restrict__ b1,
                                              f16* __restrict__ E,
                                              float* __restrict__ rowacc) {
  __shared__ u16 smem[2 * 128 * 128];
  u16* lA = smem;
  u16* lB = smem + 128 * 128;
  const int bx = blockIdx.x, by = blockIdx.y, bz = blockIdx.z;
  const int tid = threadIdx.x;
  const int lane = tid & 63, wave = tid >> 6;

  const u16* gA = b0 + (size_t)bz * LL * CC + (size_t)by * 128 * CC;
  const u16* gB = b1 + (size_t)bz * SS * CC + (size_t)bx * 128 * CC;

#pragma unroll
  for (int i = 0; i < 8; ++i) {
    const int c = i * 256 + tid;
    const int row = c >> 4;
    const int slot = c & 15;
    const int kchunk = slot ^ (row & 7);
    const size_t soff = (size_t)row * CC + kchunk * 8;
    const int ldsoff = (i * 256 + wave * 64) * 16;
    gload_lds16(gA + soff, (char*)lA + ldsoff);
    gload_lds16(gB + soff, (char*)lB + ldsoff);
  }
  __syncthreads();

  const int wr = wave >> 1, wc = wave & 1;
  f32x4 acc[4][4];
#pragma unroll
  for (int i = 0; i < 4; ++i)
#pragma unroll
    for (int j = 0; j < 4; ++j) acc[i][j] = (f32x4){0.f, 0.f, 0.f, 0.f};

#pragma unroll
  for (int ks = 0; ks < 4; ++ks) {
    short8 af[4], bfr[4];
#pragma unroll
    for (int mi = 0; mi < 4; ++mi) {
      const int row = wr * 64 + mi * 16 + (lane & 15);
      const int kc = ks * 4 + (lane >> 4);
      af[mi] = *(const short8*)&lA[row * 128 + (kc ^ (row & 7)) * 8];
    }
#pragma unroll
    for (int ni = 0; ni < 4; ++ni) {
      const int row = wc * 64 + ni * 16 + (lane & 15);
      const int kc = ks * 4 + (lane >> 4);
      bfr[ni] = *(const short8*)&lB[row * 128 + (kc ^ (row & 7)) * 8];
    }
#pragma unroll
    for (int mi = 0; mi < 4; ++mi)
#pragma unroll
      for (int ni = 0; ni < 4; ++ni)
        acc[mi][ni] = __builtin_amdgcn_mfma_f32_16x16x32_bf16(af[mi], bfr[ni], acc[mi][ni], 0, 0, 0);
  }

  __syncthreads();                       // all LDS fragment reads done
  f16* st = (f16*)smem;                  // staging, row stride 136 f16 (16B-aligned rows)
  const float scale = 1.0f / 128.0f;
#pragma unroll
  for (int mi = 0; mi < 4; ++mi) {
    float rs[4] = {0.f, 0.f, 0.f, 0.f};
    const int lr0 = wr * 64 + mi * 16 + (lane >> 4) * 4;
#pragma unroll
    for (int ni = 0; ni < 4; ++ni) {
      const int lc = wc * 64 + ni * 16 + (lane & 15);
      f32x4 a = acc[mi][ni];
#pragma unroll
      for (int r = 0; r < 4; ++r) {
        const f16 eh = (f16)__expf(a[r] * scale);
        st[(lr0 + r) * 136 + lc] = eh;
        rs[r] += (float)eh;
      }
    }
#pragma unroll
    for (int m = 1; m < 16; m <<= 1)
#pragma unroll
      for (int r = 0; r < 4; ++r) rs[r] += __shfl_xor(rs[r], m, 64);
    if ((lane & 15) == 0) {
#pragma unroll
      for (int r = 0; r < 4; ++r)
        atomicAdd(&rowacc[bz * LL + by * 128 + lr0 + r], rs[r]);
    }
  }
  __syncthreads();
  // vectorized copy-out: 2048 16B chunks, 256B contiguous segments per row
  const size_t ebase = (size_t)bz * LL * SS + (size_t)(by * 128) * SS + (size_t)(bx * 128);
#pragma unroll
  for (int i = 0; i < 8; ++i) {
    const int c = i * 256 + tid;
    const int row = c >> 4, c16 = c & 15;
    f16x8 vv = *(const f16x8*)&st[row * 136 + c16 * 8];
    *(f16x8*)&E[ebase + (size_t)row * SS + c16 * 8] = vv;
  }
}

// ---------- iter-1 column pass: eu1 from rowacc in-block; colacc1 += eu1*E (single E read) ----------
__global__ __launch_bounds__(512) void k_col1(const f16* __restrict__ E,
                                              const float* __restrict__ rowacc,
                                              float* __restrict__ c1g,
                                              const float* __restrict__ alpha_p) {
  __shared__ float eu_lds[32];
  const int b = blockIdx.y, strip = blockIdx.x, t = threadIdx.x;
  const float EA = __expf(*alpha_p);
  const float enorm = 1.0f / 8192.0f;
  if (t < 32) eu_lds[t] = enorm / (rowacc[(size_t)b * LL + strip * 32 + t] + EA);
  __syncthreads();
  const f16* Eb = E + (size_t)b * LL * SS + (size_t)strip * 32 * SS;
  float acc[8];
#pragma unroll
  for (int e = 0; e < 8; ++e) acc[e] = 0.f;
  for (int r = 0; r < 32; ++r) {
    const f16x8 h = *(const f16x8*)(Eb + (size_t)r * SS + t * 8);
    const float eu = eu_lds[r];
#pragma unroll
    for (int e = 0; e < 8; ++e) acc[e] += eu * (float)h[e];
  }
  float* co = c1g + (size_t)b * SS;
#pragma unroll
  for (int e = 0; e < 8; ++e) atomicAdd(&co[t * 8 + e], acc[e]);
}

// ---------- fused Sinkhorn iteration (2 or 3): per row dot->eu->accumulate, single E read ----------
template <int ITER>
__global__ __launch_bounds__(512) void k_iter(const f16* __restrict__ E,
                                              const float* __restrict__ rowacc,
                                              const float* __restrict__ c1g,
                                              const float* __restrict__ cing,
                                              float* __restrict__ coutg,
                                              float* __restrict__ eu3g,
                                              float* __restrict__ s2g,
                                              const float* __restrict__ alpha_p) {
  __shared__ float ev_lds[4096];
  __shared__ float red[8];
  __shared__ float redr[16];
  const int b = blockIdx.y, strip = blockIdx.x;
  const int t = threadIdx.x, lane = t & 63, wave = t >> 6;
  const float alpha = *alpha_p;
  const float EA = __expf(alpha), HE = 0.5f * __expf(-alpha);
  const float enorm = 1.0f / 8192.0f;
  const float EU1BIN = HE / 4097.0f, BTV1 = 0.5f / 4097.0f;
  const float* ra = rowacc + (size_t)b * LL;
  const float* c1 = c1g + (size_t)b * SS;
  const float* ci = cing + (size_t)b * SS;

  float p1 = 0.f, p2 = 0.f;
  if (ITER == 2) {
    for (int i = t; i < 4096; i += 512) {
      const float e1 = enorm / (ci[i] + BTV1);   // ev1
      ev_lds[i] = e1;
      p1 += e1;
      p2 += enorm / (ra[i] + EA);                // eu1
    }
  } else {
    for (int i = t; i < 4096; i += 512) {
      p1 += enorm / (c1[i] + BTV1);              // ev1 (sum only)
      p2 += enorm / (ra[i] + EA);                // eu1
    }
  }
  const float sev1 = block_sum<8>(p1, red, t);
  const float sa1 = block_sum<8>(p2, red, t);
  const float ev1bin = HE / (sa1 + EU1BIN);
  float btu;
  if (ITER == 2) {
    btu = EA * ev1bin;
  } else {
    const float eu2bin = HE / (sev1 + ev1bin);
    const float btv2 = EA * eu2bin;
    for (int i = t; i < 4096; i += 512) ev_lds[i] = enorm / (ci[i] + btv2);  // ev2
    const float ev2bin = HE / (s2g[b] + eu2bin);
    btu = EA * ev2bin;
    __syncthreads();
  }

  // hoist this thread's ev slice to registers
  const f32x4 ev0r = *(const f32x4*)&ev_lds[t * 8];
  const f32x4 ev1r = *(const f32x4*)&ev_lds[t * 8 + 4];

  const f16* Eb = E + (size_t)b * LL * SS + (size_t)strip * 32 * SS;
  float acc[8];
#pragma unroll
  for (int e = 0; e < 8; ++e) acc[e] = 0.f;
  float seu = 0.f;

  for (int r = 0; r < 32; ++r) {
    const f16x8 h = *(const f16x8*)(Eb + (size_t)r * SS + t * 8);
    float d = 0.f;
#pragma unroll
    for (int e = 0; e < 4; ++e) d += (float)h[e] * ev0r[e];
#pragma unroll
    for (int e = 0; e < 4; ++e) d += (float)h[4 + e] * ev1r[e];
#pragma unroll
    for (int m = 1; m < 64; m <<= 1) d += __shfl_xor(d, m, 64);
    if (lane == 0) redr[(r & 1) * 8 + wave] = d;
    __syncthreads();
    float rowdot = 0.f;
#pragma unroll
    for (int w = 0; w < 8; ++w) rowdot += redr[(r & 1) * 8 + w];
    const float eu = enorm / (rowdot + btu);
    if (ITER == 3 && t == 0) eu3g[(size_t)b * LL + strip * 32 + r] = eu;
    if (ITER == 2 && t == 0) seu += eu;
#pragma unroll
    for (int e = 0; e < 4; ++e) acc[e] += eu * (float)h[e];
#pragma unroll
    for (int e = 0; e < 4; ++e) acc[4 + e] += eu * (float)h[4 + e];
  }

  float* co = coutg + (size_t)b * SS;
#pragma unroll
  for (int e = 0; e < 8; ++e) atomicAdd(&co[t * 8 + e], acc[e]);
  if (ITER == 2 && t == 0) atomicAdd(&s2g[b], seu);
}

// ---------- final: ev3 from colacc3 (register slice), out = E*eu3[l]*ev3[s]*8192 ----------
__global__ __launch_bounds__(256) void k_finalize(const f16* __restrict__ E,
                                                  float* __restrict__ out,
                                                  const float* __restrict__ rowacc,
                                                  const float* __restrict__ c1g,
                                                  const float* __restrict__ c2g,
                                                  const float* __restrict__ c3g,
                                                  const float* __restrict__ eu3g,
                                                  const float* __restrict__ s2g,
                                                  const float* __restrict__ alpha_p) {
  __shared__ float red[4];
  __shared__ float eu_s[16];
  const int b = blockIdx.y, rb = blockIdx.x;
  const int t = threadIdx.x, lane = t & 63, wave = t >> 6;
  const float alpha = *alpha_p;
  const float EA = __expf(alpha), HE = 0.5f * __expf(-alpha);
  const float enorm = 1.0f / 8192.0f;
  const float EU1BIN = HE / 4097.0f, BTV1 = 0.5f / 4097.0f;
  const float* ra = rowacc + (size_t)b * LL;
  const float* c1 = c1g + (size_t)b * SS;
  const float* c2 = c2g + (size_t)b * SS;
  const float* c3 = c3g + (size_t)b * SS;

  float p1 = 0.f, p2 = 0.f;
  for (int i = t; i < 4096; i += 256) {
    p1 += enorm / (c1[i] + BTV1);
    p2 += enorm / (ra[i] + EA);
  }
  const float sev1 = block_sum<4>(p1, red, t);
  const float sa1 = block_sum<4>(p2, red, t);
  const float ev1bin = HE / (sa1 + EU1BIN);
  const float eu2bin = HE / (sev1 + ev1bin);
  const float btv2 = EA * eu2bin;
  float p3 = 0.f;
  for (int i = t; i < 4096; i += 256) p3 += enorm / (c2[i] + btv2);
  const float sev2 = block_sum<4>(p3, red, t);
  const float ev2bin = HE / (s2g[b] + eu2bin);
  const float eu3bin = HE / (sev2 + ev2bin);
  const float btv3 = EA * eu3bin;

  if (t < 16) eu_s[t] = eu3g[(size_t)b * LL + rb * 16 + t] * 8192.0f;

  // per-thread ev3 register slice for its (it,lane) chunks
  f32x4 evr[16];
#pragma unroll
  for (int it = 0; it < 8; ++it) {
    const int base = (it * 64 + lane) * 8;
    f32x4 q0 = *(const f32x4*)&c3[base];
    f32x4 q1 = *(const f32x4*)&c3[base + 4];
    f32x4 r0, r1;
#pragma unroll
    for (int e = 0; e < 4; ++e) { r0[e] = enorm / (q0[e] + btv3); r1[e] = enorm / (q1[e] + btv3); }
    evr[it * 2] = r0;
    evr[it * 2 + 1] = r1;
  }
  __syncthreads();

  const size_t rbase = (size_t)b * LL * SS + (size_t)(rb * 16) * SS;
#pragma unroll
  for (int rr = 0; rr < 4; ++rr) {
    const int rloc = wave * 4 + rr;
    const float a = eu_s[rloc];
    const f16x8* rowp = (const f16x8*)(E + rbase + (size_t)rloc * SS);
    f32x4* orow = (f32x4*)(out + rbase + (size_t)rloc * SS);
#pragma unroll
    for (int it = 0; it < 8; ++it) {
      const f16x8 h = rowp[it * 64 + lane];
      f32x4 o0, o1;
#pragma unroll
      for (int e = 0; e < 4; ++e) o0[e] = (float)h[e] * a * evr[it * 2][e];
#pragma unroll
      for (int e = 0; e < 4; ++e) o1[e] = (float)h[4 + e] * a * evr[it * 2 + 1][e];
      orow[2 * (it * 64 + lane)] = o0;
      orow[2 * (it * 64 + lane) + 1] = o1;
    }
  }
}

// ---------- launch ----------
extern "C" void kernel_launch(void* const* d_in, const int* in_sizes, int n_in,
                              void* d_out, int out_size, void* d_ws, size_t ws_size,
                              hipStream_t stream) {
  const float* f0 = (const float*)d_in[0];
  const float* f1 = (const float*)d_in[1];
  const float* alpha_p = (const float*)d_in[2];
  float* out = (float*)d_out;

  char* ws = (char*)d_ws;
  size_t off = (size_t)NB * LL * SS * 2;               // E: 128 MiB
  f16* E = (f16*)ws;
  u16* b0 = (u16*)(ws + off);  off += (size_t)NB * LL * CC * 2;
  u16* b1 = (u16*)(ws + off);  off += (size_t)NB * SS * CC * 2;
  float* rowacc = (float*)(ws + off); off += (size_t)NB * LL * 4;
  float* c1 = (float*)(ws + off);     off += (size_t)NB * SS * 4;
  float* c2 = (float*)(ws + off);     off += (size_t)NB * SS * 4;
  float* c3 = (float*)(ws + off);     off += (size_t)NB * SS * 4;
  float* s2 = (float*)(ws + off);     off += 256;
  float* eu3g = (float*)(ws + off);   off += (size_t)NB * LL * 4;

  // zero rowacc + c1 + c2 + c3 + s2 in one contiguous memset
  hipMemsetAsync(rowacc, 0, (size_t)NB * (LL + 3 * SS) * 4 + 256, stream);

  k_convert<<<2048, 256, 0, stream>>>(f0, f1, b0, b1);
  k_gemm<<<dim3(SS / 128, LL / 128, NB), 256, 0, stream>>>(b0, b1, E, rowacc);
  k_col1<<<dim3(LL / 32, NB), 512, 0, stream>>>(E, rowacc, c1, alpha_p);
  k_iter<2><<<dim3(LL / 32, NB), 512, 0, stream>>>(E, rowacc, c1, c1, c2, eu3g, s2, alpha_p);
  k_iter<3><<<dim3(LL / 32, NB), 512, 0, stream>>>(E, rowacc, c1, c2, c3, eu3g, s2, alpha_p);
  k_finalize<<<dim3(LL / 16, NB), 256, 0, stream>>>(E, out, rowacc, c1, c2, c3, eu3g, s2, alpha_p);
}